// Round 9
// baseline (1995.616 us; speedup 1.0000x reference)
//
#include <hip/hip_runtime.h>
#include <math.h>

#define N1 1024
#define NN2 (N1*N1)
#define LL 16384

// ---------------- prep: e = (d/2)A ; zero split-K flags ----------------
__global__ __launch_bounds__(256) void k_prep(const float* __restrict__ A,
                                              const float* __restrict__ logd,
                                              float* __restrict__ e,
                                              int* __restrict__ flags) {
    int b = blockIdx.x, t = threadIdx.x;
    if (b < 4096) {
        int i = b * 256 + t;
        float d = expf(logd[0]);
        e[i] = 0.5f * d * A[i];
    } else {
        if (t < 256) flags[t] = 0;
    }
}

__global__ __launch_bounds__(256) void k_add(const float* __restrict__ a,
                                             const float* __restrict__ b,
                                             float* __restrict__ o) {
    int i = blockIdx.x * 256 + threadIdx.x;
    o[i] = a[i] + b[i];
}

// ---------------- fused: [512 GEMM blocks | 16w chain blocks] ----------------
// GEMM: 64x64 tile, BK=32 dbuf, 4x4/thread, split-K2 (z=0/1, K=512 each).
// Tail-combine: 2nd arriver per tile does Cout = alpha*(p0+p1) + beta*Aadd.
// Chain (kc=1): mode0: V[w+i] = (I+Dm)V[i] (rows); mode1: V[w+i] = V[i](I+Dm) (cols).
__global__ __launch_bounds__(256) void k_fused(const float* __restrict__ GA,
                                               const float* __restrict__ GB,
                                               float* __restrict__ MP,
                                               float* __restrict__ Cout,
                                               const float* __restrict__ Aadd,
                                               float alpha, float beta,
                                               int* __restrict__ flags,
                                               const float* __restrict__ Dm,
                                               float* __restrict__ V,
                                               int w, int mode) {
    __shared__ __align__(16) char smem[34816];
    __shared__ int sflag;
    int b = blockIdx.x, t = threadIdx.x;

    if (b >= 512) {                       // ---- chain block ----
        int cb = b - 512;
        int i = cb >> 4, nx = cb & 15, n0 = nx * 64;
        float* sV  = (float*)smem;
        float* red = (float*)(smem + 4096);
        const float* Vi = V + (size_t)i * N1;
        *(float4*)&sV[t * 4] = *(const float4*)&Vi[t * 4];
        __syncthreads();
        int wave = t >> 6, lane = t & 63;
        if (mode == 0) {
            for (int rr = 0; rr < 16; ++rr) {
                int n = n0 + wave * 16 + rr;
                const float* Mr = Dm + (size_t)n * N1;
                float acc = 0.f;
#pragma unroll
                for (int jj = 0; jj < 4; ++jj) {
                    int m = jj * 256 + lane * 4;
                    float4 a = *(const float4*)&Mr[m];
                    float4 v = *(const float4*)&sV[m];
                    acc += a.x * v.x + a.y * v.y + a.z * v.z + a.w * v.w;
                }
#pragma unroll
                for (int off = 32; off > 0; off >>= 1) acc += __shfl_down(acc, off, 64);
                if (lane == 0) V[(size_t)(w + i) * N1 + n] = sV[n] + acc;
            }
        } else {
            int n = n0 + lane;
            int mb = wave * 256;
            float acc = 0.f;
#pragma unroll 8
            for (int m = 0; m < 256; ++m)
                acc += sV[mb + m] * Dm[(size_t)(mb + m) * N1 + n];
            red[wave * 64 + lane] = acc;
            __syncthreads();
            if (t < 64) {
                float s = red[t] + red[64 + t] + red[128 + t] + red[192 + t];
                V[(size_t)(w + i) * N1 + n0 + t] = sV[n0 + t] + s;
            }
        }
        return;
    }

    // ---- GEMM block ----
    float* As = (float*)smem;             // [2][32][68]
    float* Bs = (float*)(smem + 17408);   // [2][32][68]
#define AS(bf, k, m) As[((bf) * 32 + (k)) * 68 + (m)]
#define BS(bf, k, m) Bs[((bf) * 32 + (k)) * 68 + (m)]
    int g = b;
    int z = g >> 8, ty = (g >> 4) & 15, tx = g & 15;
    int m0 = ty * 64, n0 = tx * 64, kz = z * 512;
    int tm = (t & 15) * 4, tn = (t >> 4) * 4;
    int lmA = t >> 2, lkA = (t & 3) * 8;
    int kbB = t >> 3, nbB = (t & 7) * 8;
    const float* Ap = GA + (size_t)(m0 + lmA) * N1 + kz + lkA;
    const float* Bp = GB + (size_t)(kz + kbB) * N1 + n0 + nbB;

    float4 pa0 = *(const float4*)(Ap);
    float4 pa1 = *(const float4*)(Ap + 4);
    float4 pb0 = *(const float4*)(Bp);
    float4 pb1 = *(const float4*)(Bp + 4);
    AS(0, lkA + 0, lmA) = pa0.x; AS(0, lkA + 1, lmA) = pa0.y;
    AS(0, lkA + 2, lmA) = pa0.z; AS(0, lkA + 3, lmA) = pa0.w;
    AS(0, lkA + 4, lmA) = pa1.x; AS(0, lkA + 5, lmA) = pa1.y;
    AS(0, lkA + 6, lmA) = pa1.z; AS(0, lkA + 7, lmA) = pa1.w;
    *(float4*)&BS(0, kbB, nbB)     = pb0;
    *(float4*)&BS(0, kbB, nbB + 4) = pb1;
    __syncthreads();

    float acc[4][4];
#pragma unroll
    for (int i = 0; i < 4; ++i)
#pragma unroll
        for (int j = 0; j < 4; ++j) acc[i][j] = 0.f;

    for (int tt = 0; tt < 16; ++tt) {
        int cur = tt & 1;
        float4 na0, na1, nb0, nb1;
        if (tt < 15) {
            int k0 = (tt + 1) * 32;
            na0 = *(const float4*)(Ap + k0);
            na1 = *(const float4*)(Ap + k0 + 4);
            nb0 = *(const float4*)(Bp + (size_t)k0 * N1);
            nb1 = *(const float4*)(Bp + (size_t)k0 * N1 + 4);
        }
#pragma unroll
        for (int k = 0; k < 32; ++k) {
            float4 a = *(float4*)&AS(cur, k, tm);
            float4 bb = *(float4*)&BS(cur, k, tn);
            acc[0][0] += a.x * bb.x; acc[0][1] += a.x * bb.y; acc[0][2] += a.x * bb.z; acc[0][3] += a.x * bb.w;
            acc[1][0] += a.y * bb.x; acc[1][1] += a.y * bb.y; acc[1][2] += a.y * bb.z; acc[1][3] += a.y * bb.w;
            acc[2][0] += a.z * bb.x; acc[2][1] += a.z * bb.y; acc[2][2] += a.z * bb.z; acc[2][3] += a.z * bb.w;
            acc[3][0] += a.w * bb.x; acc[3][1] += a.w * bb.y; acc[3][2] += a.w * bb.z; acc[3][3] += a.w * bb.w;
        }
        if (tt < 15) {
            int nx_ = cur ^ 1;
            AS(nx_, lkA + 0, lmA) = na0.x; AS(nx_, lkA + 1, lmA) = na0.y;
            AS(nx_, lkA + 2, lmA) = na0.z; AS(nx_, lkA + 3, lmA) = na0.w;
            AS(nx_, lkA + 4, lmA) = na1.x; AS(nx_, lkA + 5, lmA) = na1.y;
            AS(nx_, lkA + 6, lmA) = na1.z; AS(nx_, lkA + 7, lmA) = na1.w;
            *(float4*)&BS(nx_, kbB, nbB)     = nb0;
            *(float4*)&BS(nx_, kbB, nbB + 4) = nb1;
            __syncthreads();
        }
    }
    // store partial
    float* Po = MP + (size_t)z * NN2;
#pragma unroll
    for (int i = 0; i < 4; ++i) {
        float4 o = {acc[i][0], acc[i][1], acc[i][2], acc[i][3]};
        *(float4*)&Po[(size_t)(m0 + tm + i) * N1 + n0 + tn] = o;
    }
    __threadfence();
    if (t == 0) sflag = atomicAdd(&flags[ty * 16 + tx], 1);
    __syncthreads();
    if (sflag == 1) {                      // second arriver combines
        __threadfence();
        const float* Pq = MP + (size_t)(1 - z) * NN2;
#pragma unroll
        for (int i = 0; i < 4; ++i) {
            size_t ri = (size_t)(m0 + tm + i) * N1 + n0 + tn;
            float4 oth = *(const float4*)&Pq[ri];
            float4 mine = {acc[i][0], acc[i][1], acc[i][2], acc[i][3]};
            float4 p0 = (z == 0) ? mine : oth;
            float4 p1 = (z == 0) ? oth : mine;
            float4 av = *(const float4*)&Aadd[ri];
            float4 o;
            o.x = alpha * (p0.x + p1.x) + beta * av.x;
            o.y = alpha * (p0.y + p1.y) + beta * av.y;
            o.z = alpha * (p0.z + p1.z) + beta * av.z;
            o.w = alpha * (p0.w + p1.w) + beta * av.w;
            *(float4*)&Cout[ri] = o;
        }
        if (t == 0) flags[ty * 16 + tx] = 0;   // self-clean for next dispatch
    }
#undef AS
#undef BS
}

// ---------------- capply: dst[i] = src[i] (I + M)  (row-vec x matrix) ------------
// grid = 16*nvec blocks
__global__ __launch_bounds__(256) void k_capply(const float* __restrict__ M,
                                                const float* __restrict__ src,
                                                float* __restrict__ dst) {
    __shared__ float sV[N1];
    __shared__ float red[4][64];
    int b = blockIdx.x, t = threadIdx.x;
    int i = b >> 4, nx = b & 15, n0 = nx * 64;
    const float* Si = src + (size_t)i * N1;
    *(float4*)&sV[t * 4] = *(const float4*)&Si[t * 4];
    __syncthreads();
    int wave = t >> 6, lane = t & 63;
    int n = n0 + lane;
    int mb = wave * 256;
    float acc = 0.f;
#pragma unroll 8
    for (int m = 0; m < 256; ++m)
        acc += sV[mb + m] * M[(size_t)(mb + m) * N1 + n];
    red[wave][lane] = acc;
    __syncthreads();
    if (t < 64) {
        float s = red[0][t] + red[1][t] + red[2][t] + red[3][t];
        dst[(size_t)i * N1 + n0 + t] = sV[n0 + t] + s;
    }
}

// ---------------- init partials: CP[ky][n] = D1[n, 64ky:64ky+64] . B ----------
__global__ __launch_bounds__(256) void k_cpart(const float* __restrict__ M,
                                               const float* __restrict__ Bv,
                                               float* __restrict__ CP) {
    __shared__ float sV[64];
    int cb = blockIdx.x, t = threadIdx.x;
    int ky = (cb >> 4) & 15, nx = cb & 15;
    int m0 = ky * 64, n0 = nx * 64;
    if (t < 16) *(float4*)&sV[t * 4] = *(const float4*)&Bv[m0 + t * 4];
    __syncthreads();
    int wave = t >> 6, lane = t & 63;
    for (int rr = 0; rr < 16; ++rr) {
        int n = n0 + wave * 16 + rr;
        const float* Mr = M + (size_t)n * N1 + m0;
        float acc = 0.f;
        if (lane < 16) {
            int m = lane * 4;
            float4 a = *(const float4*)&Mr[m];
            float4 v = *(const float4*)&sV[m];
            acc = a.x * v.x + a.y * v.y + a.z * v.z + a.w * v.w;
        }
#pragma unroll
        for (int off = 8; off > 0; off >>= 1) acc += __shfl_down(acc, off, 64);
        if (lane == 0) CP[(size_t)ky * N1 + n] = acc;
    }
}

// ---------------- init reduce: Q[0] = d*(B + 0.5*D1@B); P[0] = C ----------------
__global__ __launch_bounds__(256) void k_initR(const float* __restrict__ Bv,
                                               const float* __restrict__ Cv,
                                               const float* __restrict__ logd,
                                               const float* __restrict__ CP,
                                               float* __restrict__ Q,
                                               float* __restrict__ P) {
    int n = blockIdx.x * 256 + threadIdx.x;
    float s = 0.f;
    for (int c = 0; c < 16; ++c) s += CP[(size_t)c * N1 + n];
    float d = expf(logd[0]);
    Q[n] = d * (Bv[n] + 0.5f * s);
    P[n] = Cv[n];
}

// ---------------- K[a*128+b] = dot(P[a], Q[b]) ----------------
__global__ __launch_bounds__(256) void k_kdot(const float* __restrict__ P,
                                              const float* __restrict__ Q,
                                              float* __restrict__ K) {
    int t = threadIdx.x;
    int wid = blockIdx.x * 4 + (t >> 6), lane = t & 63;
    int a = wid >> 7, b = wid & 127;
    const float* Pr = P + (size_t)a * N1;
    const float* Qr = Q + (size_t)b * N1;
    float acc = 0.f;
#pragma unroll
    for (int jj = 0; jj < 4; ++jj) {
        int m = jj * 256 + lane * 4;
        float4 p = *(const float4*)&Pr[m];
        float4 q = *(const float4*)&Qr[m];
        acc += p.x * q.x + p.y * q.y + p.z * q.z + p.w * q.w;
    }
#pragma unroll
    for (int off = 32; off > 0; off >>= 1) acc += __shfl_down(acc, off, 64);
    if (lane == 0) K[wid] = acc;
}

// ---------------- conv phase 1 ----------------
__global__ __launch_bounds__(256) void k_conv1(const float* __restrict__ X,
                                               const float* __restrict__ K,
                                               float* __restrict__ part) {
    __shared__ __align__(16) float ks[1280];
    __shared__ __align__(16) float xs[256];
    int bx = blockIdx.x, tt = threadIdx.x;
    int o = 0;
    while (bx >= 2 * (o + 1) * (o + 1) + 2 * (o + 1)) ++o;
    int jt = bx - (2 * o * o + 2 * o);
    int T0 = o * 1024, J0 = jt * 256;
    int mb = T0 - J0 - 255;
    for (int ii = tt; ii < 1280; ii += 256) {
        int m = mb + ii;
        ks[ii] = (m >= 0 && m < LL) ? K[m] : 0.f;
    }
    xs[tt] = X[J0 + tt];
    __syncthreads();

    float acc0 = 0.f, acc1 = 0.f, acc2 = 0.f, acc3 = 0.f;
    int base0 = 4 * tt + 252;
#pragma unroll 4
    for (int jj = 0; jj < 256; jj += 4) {
        float4 xv  = *(const float4*)&xs[jj];
        float4 kv0 = *(const float4*)&ks[base0 - jj];
        float4 kv1 = *(const float4*)&ks[base0 - jj + 4];
        float kk0 = kv0.x, kk1 = kv0.y, kk2 = kv0.z, kk3 = kv0.w;
        float kk4 = kv1.x, kk5 = kv1.y, kk6 = kv1.z;
        acc0 += kk3 * xv.x + kk2 * xv.y + kk1 * xv.z + kk0 * xv.w;
        acc1 += kk4 * xv.x + kk3 * xv.y + kk2 * xv.z + kk1 * xv.w;
        acc2 += kk5 * xv.x + kk4 * xv.y + kk3 * xv.z + kk2 * xv.w;
        acc3 += kk6 * xv.x + kk5 * xv.y + kk4 * xv.z + kk3 * xv.w;
    }
    float4 out = {acc0, acc1, acc2, acc3};
    *(float4*)&part[((size_t)(o * 64 + jt)) * 1024 + 4 * tt] = out;
}

// ---------------- conv phase 2 ----------------
__global__ __launch_bounds__(256) void k_conv2(const float* __restrict__ X,
                                               const float* __restrict__ part,
                                               const float* __restrict__ Dp,
                                               float* __restrict__ Y) {
    int o = blockIdx.x, tt = threadIdx.x;
    int c = 4 * tt;
    float s0 = 0.f, s1 = 0.f, s2 = 0.f, s3 = 0.f;
    int cnt = 4 * o + 4;
    for (int jt = 0; jt < cnt; ++jt) {
        float4 p = *(const float4*)&part[((size_t)(o * 64 + jt)) * 1024 + c];
        s0 += p.x; s1 += p.y; s2 += p.z; s3 += p.w;
    }
    float dsk = Dp[0];
    int t = o * 1024 + c;
    float4 xv = *(const float4*)&X[t];
    float4 out;
    out.x = dsk * xv.x + s0;
    out.y = dsk * xv.y + s1;
    out.z = dsk * xv.z + s2;
    out.w = dsk * xv.w + s3;
    *(float4*)&Y[t] = out;
}

extern "C" void kernel_launch(void* const* d_in, const int* in_sizes, int n_in,
                              void* d_out, int out_size, void* d_ws, size_t ws_size,
                              hipStream_t stream) {
    const float* X    = (const float*)d_in[0];
    const float* A    = (const float*)d_in[1];
    const float* Bv   = (const float*)d_in[2];
    const float* Cv   = (const float*)d_in[3];
    const float* Dp   = (const float*)d_in[4];
    const float* logd = (const float*)d_in[5];
    float* ws = (float*)d_ws;

    float* S0 = ws;                         // e, D ping-pong
    float* S1 = ws + (size_t)NN2;           // e^2
    float* S2 = ws + 2 * (size_t)NN2;       // e^2+e^4
    float* S3 = ws + 3 * (size_t)NN2;       // t1
    float* S4 = ws + 4 * (size_t)NN2;       // D1, ping-pong
    float* MP = ws + 5 * (size_t)NN2;       // 2x NN2 split-K partials; conv partials
    float* CP = ws + 7 * (size_t)NN2;       // init partials (16 x N1)
    float* T1 = CP + 64 * (size_t)N1;       // capply temp (64 vec)
    float* T2 = T1 + 64 * (size_t)N1;       // capply temp (64 vec)
    float* Qv = T2 + 64 * (size_t)N1;       // 128 x N1
    float* Pv = Qv + 128 * (size_t)N1;      // 128 x N1
    float* Kc = Pv + 128 * (size_t)N1;      // LL
    int* flags = (int*)(Kc + LL);           // 256 split-K flags
    float* Y  = (float*)d_out;

    // e = (d/2)A ; zero flags
    k_prep<<<4097, 256, 0, stream>>>(A, logd, S0, flags);
    // D1 = 2e(I+e)(I+e^2+e^4):
    k_fused<<<512, 256, 0, stream>>>(S0, S0, MP, S1, S0, 1.f, 0.f, flags, S0, nullptr, 0, 0);  // e^2
    k_fused<<<512, 256, 0, stream>>>(S1, S1, MP, S2, S1, 1.f, 1.f, flags, S0, nullptr, 0, 0);  // e^2+e^4
    k_add<<<4096, 256, 0, stream>>>(S0, S1, S3);                                                // t1 = e+e^2
    k_fused<<<512, 256, 0, stream>>>(S3, S2, MP, S4, S3, 2.f, 2.f, flags, S0, nullptr, 0, 0);  // D1

    // init: Q0 = d*(B + 0.5*D1@B); P0 = C
    k_cpart<<<256, 256, 0, stream>>>(S4, Bv, CP);
    k_initR<<<4, 256, 0, stream>>>(Bv, Cv, logd, CP, Qv, Pv);

    float* cur = S4;
    float* nxt = S0;
    // Q loop: chain w=2^k with D_{2^k} fused with squaring -> D_{2^{k+1}}
    for (int k = 0; k < 7; ++k) {
        int w = 1 << k;
        k_fused<<<512 + 16 * w, 256, 0, stream>>>(cur, cur, MP, nxt, cur, 1.f, 2.f, flags, cur, Qv, w, 0);
        float* ts = cur; cur = nxt; nxt = ts;
    }
    // P loop (squarings kept only to D_2048): k=0..3, w=1..8 with D_128..D_1024
    for (int k = 0; k < 4; ++k) {
        int w = 1 << k;
        k_fused<<<512 + 16 * w, 256, 0, stream>>>(cur, cur, MP, nxt, cur, 1.f, 2.f, flags, cur, Pv, w, 1);
        float* ts = cur; cur = nxt; nxt = ts;
    }
    // cur = D_2048. Multi-apply for w=16/32/64 (dA^2048 per pass):
    k_capply<<<256, 256, 0, stream>>>(cur, Pv, Pv + 16 * (size_t)N1);            // w=16
    k_capply<<<512, 256, 0, stream>>>(cur, Pv, T1);                               // w=32 pass1
    k_capply<<<512, 256, 0, stream>>>(cur, T1, Pv + 32 * (size_t)N1);             // w=32 pass2
    k_capply<<<1024, 256, 0, stream>>>(cur, Pv, T1);                              // w=64 pass1
    k_capply<<<1024, 256, 0, stream>>>(cur, T1, T2);                              // pass2
    k_capply<<<1024, 256, 0, stream>>>(cur, T2, T1);                              // pass3
    k_capply<<<1024, 256, 0, stream>>>(cur, T1, Pv + 64 * (size_t)N1);            // pass4

    k_kdot<<<4096, 256, 0, stream>>>(Pv, Qv, Kc);
    k_conv1<<<544, 256, 0, stream>>>(X, Kc, MP);
    k_conv2<<<16, 256, 0, stream>>>(X, MP, Dp, Y);
}